// Round 2
// baseline (47308.752 us; speedup 1.0000x reference)
//
#include <hip/hip_runtime.h>

#define HDIM 256
#define LSEQ 512
#define PRED 96
#define NTHR 1024

__device__ __forceinline__ float sigm(float x) { return 1.f / (1.f + __expf(-x)); }
// tanh(x) = 1 - 2/(e^{2x}+1); NaN-free at +/-inf
__device__ __forceinline__ float tanh_(float x) { float t = __expf(2.f * x); return 1.f - 2.f / (t + 1.f); }

struct SmemT {
  float h[2][4][68];    // [buf][quad][64 + pad4] fp32 hidden state; 68-stride keeps the
                        // 4 quad segments on disjoint banks (68q mod 32 = 4q)
  float stg[2][4][68];  // layer-1 input staging, same layout
  float xv[LSEQ];
  float wih[768];       // rank-1 input weights for scalar-input phases
  float bih[768];
  float bhh[768];
  float wo[HDIM];
  float red[16];
  float inp;
};

// Load this thread's 3 gate rows (64-wide fp32 k-slice) of a [768][256] matrix into
// registers. Fully unrolled -> compile-time indices -> stays in VGPRs.
#define LOADW(A, PTR)                                                              \
  {                                                                                \
    _Pragma("unroll") for (int g = 0; g < 3; ++g) {                                \
      const float4* rp = (const float4*)((PTR) + (j + (g << 8)) * HDIM + k0);      \
      _Pragma("unroll") for (int p = 0; p < 16; ++p) {                             \
        float4 f = rp[p];                                                          \
        (A)[g * 64 + 4 * p + 0] = f.x; (A)[g * 64 + 4 * p + 1] = f.y;              \
        (A)[g * 64 + 4 * p + 2] = f.z; (A)[g * 64 + 4 * p + 3] = f.w;              \
      }                                                                            \
    }                                                                              \
  }

// 3-gate partial dot over this thread's 64-wide k-slice, then combine the 4 quads
// (lanes tid^1, tid^2 — same wave since 4 | 64).
#define MATVEC(A, HP)                                                              \
  {                                                                                \
    ar = 0.f; az = 0.f; an = 0.f;                                                  \
    const float4* hp4 = (const float4*)(HP);                                       \
    _Pragma("unroll") for (int p = 0; p < 16; ++p) {                               \
      float4 hv = hp4[p];                                                          \
      ar = fmaf((A)[4 * p + 0], hv.x, ar); ar = fmaf((A)[4 * p + 1], hv.y, ar);    \
      ar = fmaf((A)[4 * p + 2], hv.z, ar); ar = fmaf((A)[4 * p + 3], hv.w, ar);    \
      az = fmaf((A)[64 + 4 * p + 0], hv.x, az); az = fmaf((A)[64 + 4 * p + 1], hv.y, az); \
      az = fmaf((A)[64 + 4 * p + 2], hv.z, az); az = fmaf((A)[64 + 4 * p + 3], hv.w, az); \
      an = fmaf((A)[128 + 4 * p + 0], hv.x, an); an = fmaf((A)[128 + 4 * p + 1], hv.y, an); \
      an = fmaf((A)[128 + 4 * p + 2], hv.z, an); an = fmaf((A)[128 + 4 * p + 3], hv.w, an); \
    }                                                                              \
    ar += __shfl_xor(ar, 1); ar += __shfl_xor(ar, 2);                              \
    az += __shfl_xor(az, 1); az += __shfl_xor(az, 2);                              \
    an += __shfl_xor(an, 1); an += __shfl_xor(an, 2);                              \
  }

__global__ __launch_bounds__(NTHR, 4) void gru_forecast(
    const float* __restrict__ x,
    const float* __restrict__ Wih0, const float* __restrict__ Whh0,
    const float* __restrict__ bih0, const float* __restrict__ bhh0,
    const float* __restrict__ Wih1, const float* __restrict__ Whh1,
    const float* __restrict__ bih1, const float* __restrict__ bhh1,
    const float* __restrict__ Wdih, const float* __restrict__ Wdhh,
    const float* __restrict__ bdih, const float* __restrict__ bdhh,
    const float* __restrict__ Wo, const float* __restrict__ bo,
    float* __restrict__ out, float* __restrict__ ys) {
  __shared__ SmemT s;
  const int tid = threadIdx.x;
  const int b = blockIdx.x;
  const int j = tid >> 2;    // output/gate row within H (0..255)
  const int q = tid & 3;     // k-quad
  const int k0 = q << 6;
  float w[192];              // recurrent weight slice (3 gates x 64 fp32)
  float wi[192];             // layer-1 input weight slice (live only in phase 2)
  float ar, az, an;

  // ---------------- Phase 1: encoder GRU layer 0 (input_size=1) ----------------
  if (tid < LSEQ) s.xv[tid] = x[(size_t)b * LSEQ + tid];
  if (tid < 768) { s.wih[tid] = Wih0[tid]; s.bih[tid] = bih0[tid]; s.bhh[tid] = bhh0[tid]; }
  if (tid < 272) ((float*)s.h[0])[tid] = 0.f;
  LOADW(w, Whh0);
  __syncthreads();

  int pb = 0;
  for (int t = 0; t < LSEQ; ++t) {
    MATVEC(w, s.h[pb][q]);
    const float xt = s.xv[t];
    const float ghr = ar + s.bhh[j], ghz = az + s.bhh[j + 256], ghn = an + s.bhh[j + 512];
    const float r = sigm(fmaf(xt, s.wih[j], s.bih[j]) + ghr);
    const float z = sigm(fmaf(xt, s.wih[j + 256], s.bih[j + 256]) + ghz);
    const float n = tanh_(fmaf(r, ghn, fmaf(xt, s.wih[j + 512], s.bih[j + 512])));
    const float hold = s.h[pb][j >> 6][j & 63];
    const float hn = fmaf(z, hold - n, n);
    if (q == 0) {
      s.h[pb ^ 1][j >> 6][j & 63] = hn;
      ys[((size_t)b * LSEQ + t) * HDIM + j] = hn;  // fp32 round-trip via ws
    }
    pb ^= 1;
    __syncthreads();
  }

  // ---- Phase 2: encoder GRU layer 1 — W_ih1 AND W_hh1 both register-resident ----
  LOADW(wi, Wih1);
  LOADW(w, Whh1);
  if (tid < 768) { s.bih[tid] = bih1[tid]; s.bhh[tid] = bhh1[tid]; }
  if (tid < 272) ((float*)s.h[0])[tid] = 0.f;
  if (tid < HDIM) s.stg[0][tid >> 6][tid & 63] = ys[((size_t)b * LSEQ + 0) * HDIM + tid];
  __syncthreads();

  pb = 0;
  for (int t = 0; t < LSEQ; ++t) {
    float nf;
    const bool ld = (t + 1 < LSEQ) && (tid < HDIM);
    if (ld) nf = ys[((size_t)b * LSEQ + t + 1) * HDIM + tid];  // prefetch next ys0
    MATVEC(wi, s.stg[t & 1][q]);                               // GI = ys0[t] @ W_ih1^T
    const float gr = ar + s.bih[j], gz = az + s.bih[j + 256], gn = an + s.bih[j + 512];
    MATVEC(w, s.h[pb][q]);                                     // GH = h @ W_hh1^T
    const float ghr = ar + s.bhh[j], ghz = az + s.bhh[j + 256], ghn = an + s.bhh[j + 512];
    const float r = sigm(gr + ghr);
    const float z = sigm(gz + ghz);
    const float n = tanh_(fmaf(r, ghn, gn));
    const float hold = s.h[pb][j >> 6][j & 63];
    const float hn = fmaf(z, hold - n, n);
    if (q == 0) s.h[pb ^ 1][j >> 6][j & 63] = hn;
    if (ld) s.stg[(t + 1) & 1][tid >> 6][tid & 63] = nf;
    pb ^= 1;
    __syncthreads();
  }

  // ---------------- Phase 3: autoregressive decoder (96 steps) ----------------
  LOADW(w, Wdhh);
  if (tid < 768) { s.wih[tid] = Wdih[tid]; s.bih[tid] = bdih[tid]; s.bhh[tid] = bdhh[tid]; }
  if (tid < HDIM) s.wo[tid] = Wo[tid];
  if (tid == 0) s.inp = 0.f;
  const float bov = bo[0];
  __syncthreads();

  for (int t = 0; t < PRED; ++t) {
    const float it = s.inp;
    MATVEC(w, s.h[pb][q]);
    const float ghr = ar + s.bhh[j], ghz = az + s.bhh[j + 256], ghn = an + s.bhh[j + 512];
    const float r = sigm(fmaf(it, s.wih[j], s.bih[j]) + ghr);
    const float z = sigm(fmaf(it, s.wih[j + 256], s.bih[j + 256]) + ghz);
    const float n = tanh_(fmaf(r, ghn, fmaf(it, s.wih[j + 512], s.bih[j + 512])));
    const float hold = s.h[pb][j >> 6][j & 63];
    const float hn = fmaf(z, hold - n, n);
    float c = (q == 0) ? s.wo[j] * hn : 0.f;
#pragma unroll
    for (int off = 1; off < 64; off <<= 1) c += __shfl_xor(c, off);
    if (q == 0) s.h[pb ^ 1][j >> 6][j & 63] = hn;
    if ((tid & 63) == 0) s.red[tid >> 6] = c;
    pb ^= 1;
    __syncthreads();
    if (tid == 0) {
      float ov = bov;
#pragma unroll
      for (int i2 = 0; i2 < 16; ++i2) ov += s.red[i2];
      out[(size_t)b * PRED + t] = ov;
      s.inp = ov;
    }
    __syncthreads();
  }
}

extern "C" void kernel_launch(void* const* d_in, const int* in_sizes, int n_in,
                              void* d_out, int out_size, void* d_ws, size_t ws_size,
                              hipStream_t stream) {
  const float* x    = (const float*)d_in[0];
  const float* Wih0 = (const float*)d_in[1];
  const float* Whh0 = (const float*)d_in[2];
  const float* bih0 = (const float*)d_in[3];
  const float* bhh0 = (const float*)d_in[4];
  const float* Wih1 = (const float*)d_in[5];
  const float* Whh1 = (const float*)d_in[6];
  const float* bih1 = (const float*)d_in[7];
  const float* bhh1 = (const float*)d_in[8];
  const float* Wdih = (const float*)d_in[9];
  const float* Wdhh = (const float*)d_in[10];
  const float* bdih = (const float*)d_in[11];
  const float* bdhh = (const float*)d_in[12];
  const float* Wo   = (const float*)d_in[13];
  const float* bo   = (const float*)d_in[14];

  // ws: ys0 fp32, 256*512*256*4 = 128 MiB
  float* ys = (float*)d_ws;

  gru_forecast<<<256, NTHR, 0, stream>>>(x, Wih0, Whh0, bih0, bhh0,
                                         Wih1, Whh1, bih1, bhh1,
                                         Wdih, Wdhh, bdih, bdhh, Wo, bo,
                                         (float*)d_out, ys);
}